// Round 2
// baseline (2809.721 us; speedup 1.0000x reference)
//
#include <hip/hip_runtime.h>
#include <hip/hip_bf16.h>

// GloAttnConv: 4 iterations of 0.5*GCN(cur) + 0.5*LinearAttn(cur), acc-sum, out-proj.
// Invariants hoisted: deg/dis/w/e_feat/msg_edge (edge-side) and k_sum (per graph).
// R1 fix: workspace was ~284 MB (likely > ws_size -> GPU page fault/abort).
//   Now q/kq/curA/curB/acc stored bf16 (fp32 accumulation), msg aliased onto d_out.
//   Total ws use ~136 MB.

using bf16 = __hip_bfloat16;
__device__ __forceinline__ float b2f(bf16 v) { return __bfloat162float(v); }
__device__ __forceinline__ bf16  f2b(float v) { return __float2bfloat16(v); }

__device__ __forceinline__ float wave_reduce_sum(float v) {
    #pragma unroll
    for (int off = 32; off > 0; off >>= 1) v += __shfl_xor(v, off, 64);
    return v;
}

// ---- graph bookkeeping -----------------------------------------------------
__global__ void k_ptr(const int* __restrict__ nn, int* __restrict__ ptr, int B) {
    if (threadIdx.x == 0 && blockIdx.x == 0) {
        int s = 0; ptr[0] = 0;
        for (int i = 0; i < B; ++i) { s += nn[i]; ptr[i + 1] = s; }
    }
}

__global__ void k_batch(const int* __restrict__ ptr, int* __restrict__ batch) {
    int b = blockIdx.x;
    int s = ptr[b], e = ptr[b + 1];
    for (int i = s + threadIdx.x; i < e; i += blockDim.x) batch[i] = b;
}

// ---- q/k projection + L2-normalize per head; also init cur & acc to h ------
__global__ __launch_bounds__(256) void k_qk(
    const float* __restrict__ x,
    const float* __restrict__ Wq_w, const float* __restrict__ Wq_b,
    const float* __restrict__ Wk_w, const float* __restrict__ Wk_b,
    bf16* __restrict__ qbuf, bf16* __restrict__ kbuf,
    bf16* __restrict__ curA, bf16* __restrict__ acc, int N)
{
    const int t = threadIdx.x;
    const int which = t >> 7;      // 0 = q, 1 = k
    const int c = t & 127;         // output column (head = c>>6, dim = c&63)
    __shared__ float xs[64];
    // W row for this thread's column lives in VGPRs for the whole block
    float4 wr[16];
    const float* W = which ? Wk_w : Wq_w;
    const float4* Wrow = (const float4*)(W + c * 64);
    #pragma unroll
    for (int j = 0; j < 16; ++j) wr[j] = Wrow[j];
    const float bias = which ? Wk_b[c] : Wq_b[c];

    int base = blockIdx.x * 64;
    for (int i = 0; i < 64; ++i) {
        int n = base + i;
        if (n >= N) break;
        __syncthreads();
        if (t < 64) xs[t] = x[n * 64 + t];
        __syncthreads();
        const float4* xs4 = (const float4*)xs;
        float s = 0.f;
        #pragma unroll
        for (int j = 0; j < 16; ++j) {
            float4 xv = xs4[j];
            s += xv.x * wr[j].x + xv.y * wr[j].y + xv.z * wr[j].z + xv.w * wr[j].w;
        }
        s += bias;
        // wave == one (which, head): lanes are the 64 dims -> per-head norm
        float ss = wave_reduce_sum(s * s);
        float o = s * rsqrtf(ss);
        (which ? kbuf : qbuf)[n * 128 + c] = f2b(o);
        if (t < 128) { float xv = xs[t & 63]; curA[n * 128 + t] = f2b(xv); acc[n * 128 + t] = f2b(xv); }
    }
}

// ---- degree / dis ----------------------------------------------------------
__global__ void k_deg(const int* __restrict__ row, int* __restrict__ deg, int E) {
    int e = blockIdx.x * 256 + threadIdx.x;
    if (e < E) atomicAdd(&deg[row[e]], 1);
}

__global__ void k_dis(const int* __restrict__ deg, float* __restrict__ dis, int N) {
    int n = blockIdx.x * 256 + threadIdx.x;
    if (n < N) { int d = deg[n]; dis[n] = d > 0 ? rsqrtf((float)d) : 0.f; }
}

// ---- exclusive scan of deg -> rowstart (3-kernel hierarchical) -------------
__global__ void k_scan1(const int* __restrict__ deg, int* __restrict__ rowstart,
                        int* __restrict__ bsum, int N) {
    __shared__ int sh[256];
    int t = threadIdx.x, n = blockIdx.x * 256 + t;
    int v = (n < N) ? deg[n] : 0;
    sh[t] = v; __syncthreads();
    #pragma unroll
    for (int off = 1; off < 256; off <<= 1) {
        int add = (t >= off) ? sh[t - off] : 0;
        __syncthreads();
        sh[t] += add;
        __syncthreads();
    }
    if (n < N) rowstart[n] = sh[t] - v;
    if (t == 255) bsum[blockIdx.x] = sh[255];
}

__global__ void k_scan2(int* __restrict__ bsum, int nb) {
    __shared__ int sh[512];
    __shared__ int carry;
    int t = threadIdx.x;
    if (t == 0) carry = 0;
    __syncthreads();
    for (int base = 0; base < nb; base += 512) {
        int idx = base + t;
        int v = (idx < nb) ? bsum[idx] : 0;
        sh[t] = v; __syncthreads();
        for (int off = 1; off < 512; off <<= 1) {
            int add = (t >= off) ? sh[t - off] : 0;
            __syncthreads();
            sh[t] += add;
            __syncthreads();
        }
        if (idx < nb) bsum[idx] = sh[t] - v + carry;
        __syncthreads();
        if (t == 0) carry += sh[511];
        __syncthreads();
    }
}

__global__ void k_scan3(int* __restrict__ rowstart, const int* __restrict__ bsum, int N, int E) {
    int n = blockIdx.x * 256 + threadIdx.x;
    if (n < N) rowstart[n] += bsum[blockIdx.x];
    if (n == 0) rowstart[N] = E;
}

// ---- CSR fill --------------------------------------------------------------
__global__ void k_fill(const int* __restrict__ eidx, const float* __restrict__ dis,
                       const int* __restrict__ rowstart, int* __restrict__ cursor,
                       int* __restrict__ csr_col, float* __restrict__ csr_w,
                       int* __restrict__ csr_eid, int E) {
    int e = blockIdx.x * 256 + threadIdx.x;
    if (e >= E) return;
    int r = eidx[e], c = eidx[E + e];
    float wv = dis[r] * dis[c];
    int slot = atomicAdd(&cursor[r], 1);
    int idx = rowstart[r] + slot;
    csr_col[idx] = c; csr_w[idx] = wv; csr_eid[idx] = e;
}

// ---- msg_edge[n,64] = sum_e w[e]*(bond0[a0]+bond1[a1]+bond2[a2]) -----------
__global__ __launch_bounds__(64) void k_msg(
    const int* __restrict__ rowstart, const int* __restrict__ csr_eid,
    const float* __restrict__ csr_w, const int* __restrict__ eattr,
    const float* __restrict__ bond, float* __restrict__ msg, int N) {
    int n = blockIdx.x, t = threadIdx.x;
    int s0 = rowstart[n], s1 = rowstart[n + 1];
    float m = 0.f;
    for (int i = s0; i < s1; ++i) {
        int e = csr_eid[i];
        float wv = csr_w[i];
        int a0 = eattr[e * 3 + 0], a1 = eattr[e * 3 + 1], a2 = eattr[e * 3 + 2];
        m += wv * (bond[a0 * 64 + t] + bond[(8 + a1) * 64 + t] + bond[(16 + a2) * 64 + t]);
    }
    msg[n * 64 + t] = m;
}

// ---- k_sum per graph (constant across iterations) --------------------------
__global__ __launch_bounds__(128) void k_ksum(
    const bf16* __restrict__ kq, const int* __restrict__ batch,
    float* __restrict__ ksum, int N) {
    int t = threadIdx.x;
    int start = blockIdx.x * 256;
    if (start >= N) return;
    int curb = batch[start];
    float a = 0.f;
    for (int i = 0; i < 256; ++i) {
        int n = start + i;
        if (n >= N) break;
        int b = batch[n];
        if (b != curb) { atomicAdd(&ksum[curb * 128 + t], a); a = 0.f; curb = b; }
        a += b2f(kq[n * 128 + t]);
    }
    atomicAdd(&ksum[curb * 128 + t], a);
}

// ---- kv[b,h,d,e] = sum_n k[n,h,d]*v[n,h,e]; v_sum[b,h,e] -------------------
__global__ __launch_bounds__(256) void k_kv(
    const bf16* __restrict__ kq, const bf16* __restrict__ cur,
    const int* __restrict__ batch, float* __restrict__ kv,
    float* __restrict__ vsum, int N)
{
    int t = threadIdx.x;
    int h = blockIdx.y;
    int start = blockIdx.x * 256;
    if (start >= N) return;
    __shared__ float kl[64], vl[64];
    int d = t >> 2, e0 = (t & 3) * 16;   // thread owns kv[d][e0..e0+15]
    float a[16];
    #pragma unroll
    for (int j = 0; j < 16; ++j) a[j] = 0.f;
    float va = 0.f;
    int curb = batch[start];
    for (int i = 0; i < 256; ++i) {
        int n = start + i;
        if (n >= N) break;
        int b = batch[n];
        if (b != curb) {   // graph boundary: flush partial sums (block-uniform branch)
            #pragma unroll
            for (int j = 0; j < 16; ++j) {
                atomicAdd(&kv[((curb * 2 + h) * 64 + d) * 64 + e0 + j], a[j]);
                a[j] = 0.f;
            }
            if (t >= 64 && t < 128) { atomicAdd(&vsum[curb * 128 + h * 64 + (t - 64)], va); va = 0.f; }
            curb = b;
        }
        __syncthreads();
        if (t < 64) kl[t] = b2f(kq[n * 128 + h * 64 + t]);
        else if (t < 128) vl[t - 64] = b2f(cur[n * 128 + h * 64 + (t - 64)]);
        __syncthreads();
        float kd = kl[d];
        #pragma unroll
        for (int j = 0; j < 16; ++j) a[j] += kd * vl[e0 + j];
        if (t >= 64 && t < 128) va += vl[t - 64];
    }
    #pragma unroll
    for (int j = 0; j < 16; ++j) atomicAdd(&kv[((curb * 2 + h) * 64 + d) * 64 + e0 + j], a[j]);
    if (t >= 64 && t < 128) atomicAdd(&vsum[curb * 128 + h * 64 + (t - 64)], va);
}

// ---- attn[n,h,e] = (q.kv + vsum) / (q.ksum + n_nodes); write 0.5*attn ------
__global__ __launch_bounds__(128) void k_attn(
    const bf16* __restrict__ q, const float* __restrict__ kv,
    const float* __restrict__ vsum, const float* __restrict__ ksum,
    const int* __restrict__ batch, const int* __restrict__ nn,
    bf16* __restrict__ curB, int N)
{
    __shared__ float kvl[8192];
    __shared__ float ql[128], vsl[128], ksl[128];
    int t = threadIdx.x;
    int start = blockIdx.x * 128;
    if (start >= N) return;
    int curb = -1;
    float nnf = 0.f;
    int h = t >> 6, e = t & 63;
    for (int i = 0; i < 128; ++i) {
        int n = start + i;
        if (n >= N) break;
        int b = batch[n];
        if (b != curb) {               // block-uniform (n shared by block)
            __syncthreads();
            for (int idx = t; idx < 8192; idx += 128) kvl[idx] = kv[b * 8192 + idx];
            vsl[t] = vsum[b * 128 + t];
            ksl[t] = ksum[b * 128 + t];
            __syncthreads();
            curb = b; nnf = (float)nn[b];
        }
        __syncthreads();
        ql[t] = b2f(q[n * 128 + t]);
        __syncthreads();
        float num = 0.f;
        #pragma unroll
        for (int dd = 0; dd < 64; ++dd) num += ql[h * 64 + dd] * kvl[(h * 64 + dd) * 64 + e];
        float dp = ql[t] * ksl[t];      // lane e doubles as d-index for the denom dot
        dp = wave_reduce_sum(dp);       // wave == one head
        float val = (num + vsl[t]) / (dp + nnf);
        curB[n * 128 + t] = f2b(0.5f * val);
    }
}

// ---- GCN gather + combine: curB = 0.5*(gather+msg) + curB(=0.5*attn); acc += -
__global__ __launch_bounds__(128) void k_gcn(
    const bf16* __restrict__ curA, const float* __restrict__ msg,
    const int* __restrict__ rowstart, const int* __restrict__ csr_col,
    const float* __restrict__ csr_w,
    bf16* __restrict__ curB, bf16* __restrict__ acc, int N)
{
    int n = blockIdx.x, t = threadIdx.x;
    int s0 = rowstart[n], s1 = rowstart[n + 1];
    float g = 0.f;
    for (int i = s0; i < s1; ++i) {
        int c = csr_col[i];
        float wv = csr_w[i];
        g += wv * b2f(curA[c * 128 + t]);  // 128 lanes -> coalesced 256B segment
    }
    int idx = n * 128 + t;
    float val = 0.5f * (g + msg[n * 64 + (t & 63)]) + b2f(curB[idx]);
    curB[idx] = f2b(val);
    acc[idx] = f2b(b2f(acc[idx]) + val);
}

// ---- out = (acc @ Wo^T + b) / 2 -------------------------------------------
__global__ __launch_bounds__(256) void k_out(
    const bf16* __restrict__ acc, const float* __restrict__ Wo_w,
    const float* __restrict__ Wo_b, float* __restrict__ out, int N)
{
    __shared__ float wol[64 * 129];   // pad 129: 2-way bank aliasing only (free)
    __shared__ float accl[512];
    int t = threadIdx.x;
    for (int idx = t; idx < 64 * 128; idx += 256) {
        int o = idx >> 7, c = idx & 127;
        wol[o * 129 + c] = Wo_w[idx];
    }
    float bias = Wo_b[t & 63];
    __syncthreads();
    int base = blockIdx.x * 64;
    for (int s = 0; s < 16; ++s) {
        int nb = base + s * 4;
        __syncthreads();
        for (int idx = t; idx < 512; idx += 256) {
            int r = idx >> 7, c = idx & 127;
            int n = nb + r;
            accl[idx] = (n < N) ? b2f(acc[n * 128 + c]) : 0.f;
        }
        __syncthreads();
        int i = t >> 6, o = t & 63;
        int n = nb + i;
        if (n < N) {
            float s2 = 0.f;
            const float4* a4 = (const float4*)(accl + i * 128);
            #pragma unroll
            for (int c4 = 0; c4 < 32; ++c4) {
                float4 av = a4[c4];
                s2 += av.x * wol[o * 129 + c4 * 4 + 0] + av.y * wol[o * 129 + c4 * 4 + 1]
                    + av.z * wol[o * 129 + c4 * 4 + 2] + av.w * wol[o * 129 + c4 * 4 + 3];
            }
            out[n * 64 + o] = (s2 + bias) * 0.5f;
        }
    }
}

extern "C" void kernel_launch(void* const* d_in, const int* in_sizes, int n_in,
                              void* d_out, int out_size, void* d_ws, size_t ws_size,
                              hipStream_t stream) {
    const float* x    = (const float*)d_in[0];
    const float* Wq_w = (const float*)d_in[1];
    const float* Wq_b = (const float*)d_in[2];
    const float* Wk_w = (const float*)d_in[3];
    const float* Wk_b = (const float*)d_in[4];
    const float* Wo_w = (const float*)d_in[5];
    const float* Wo_b = (const float*)d_in[6];
    const float* bond = (const float*)d_in[7];
    const int*   eidx = (const int*)d_in[8];
    const int*   eattr= (const int*)d_in[9];
    const int*   nn   = (const int*)d_in[10];
    float* out = (float*)d_out;
    int N = in_sizes[0] / 64;
    int E = in_sizes[9] / 3;
    int B = in_sizes[10];

    char* p = (char*)d_ws;
    auto alloc = [&](size_t bytes) { char* r = p; p += (bytes + 255) & ~(size_t)255; return r; };
    bf16* q      = (bf16*)alloc((size_t)N * 128 * 2);
    bf16* kq     = (bf16*)alloc((size_t)N * 128 * 2);
    bf16* curA   = (bf16*)alloc((size_t)N * 128 * 2);
    bf16* curB   = (bf16*)alloc((size_t)N * 128 * 2);
    bf16* acc    = (bf16*)alloc((size_t)N * 128 * 2);
    float* kv    = (float*)alloc((size_t)B * 2 * 64 * 64 * 4);
    float* vsum  = (float*)alloc((size_t)B * 128 * 4);
    float* ksum  = (float*)alloc((size_t)B * 128 * 4);
    float* dis   = (float*)alloc((size_t)N * 4);
    int* deg     = (int*)alloc((size_t)N * 4);
    int* rowstart= (int*)alloc((size_t)(N + 1) * 4);
    int* cursor  = (int*)alloc((size_t)N * 4);
    int* csr_col = (int*)alloc((size_t)E * 4);
    float* csr_w = (float*)alloc((size_t)E * 4);
    int* csr_eid = (int*)alloc((size_t)E * 4);
    int* batch   = (int*)alloc((size_t)N * 4);
    int* ptr     = (int*)alloc((size_t)(B + 1) * 4);
    int nb = (N + 255) / 256;
    int* bsum    = (int*)alloc((size_t)nb * 4);
    float* msg   = out;   // [N,64] fp32 == out_size; fully rewritten by k_out at the end

    hipMemsetAsync(deg,    0, (size_t)N * 4, stream);
    hipMemsetAsync(cursor, 0, (size_t)N * 4, stream);
    hipMemsetAsync(ksum,   0, (size_t)B * 128 * 4, stream);

    k_ptr  <<<1, 64, 0, stream>>>(nn, ptr, B);
    k_batch<<<B, 256, 0, stream>>>(ptr, batch);
    k_qk   <<<(N + 63) / 64, 256, 0, stream>>>(x, Wq_w, Wq_b, Wk_w, Wk_b, q, kq, curA, acc, N);
    k_deg  <<<(E + 255) / 256, 256, 0, stream>>>(eidx, deg, E);
    k_dis  <<<(N + 255) / 256, 256, 0, stream>>>(deg, dis, N);
    k_scan1<<<nb, 256, 0, stream>>>(deg, rowstart, bsum, N);
    k_scan2<<<1, 512, 0, stream>>>(bsum, nb);
    k_scan3<<<nb, 256, 0, stream>>>(rowstart, bsum, N, E);
    k_fill <<<(E + 255) / 256, 256, 0, stream>>>(eidx, dis, rowstart, cursor, csr_col, csr_w, csr_eid, E);
    k_msg  <<<N, 64, 0, stream>>>(rowstart, csr_eid, csr_w, eattr, bond, msg, N);
    k_ksum <<<(N + 255) / 256, 128, 0, stream>>>(kq, batch, ksum, N);

    for (int it = 0; it < 4; ++it) {
        hipMemsetAsync(kv,   0, (size_t)B * 2 * 64 * 64 * 4, stream);
        hipMemsetAsync(vsum, 0, (size_t)B * 128 * 4, stream);
        dim3 gkv((N + 255) / 256, 2);
        k_kv  <<<gkv, 256, 0, stream>>>(kq, curA, batch, kv, vsum, N);
        k_attn<<<(N + 127) / 128, 128, 0, stream>>>(q, kv, vsum, ksum, batch, nn, curB, N);
        k_gcn <<<N, 128, 0, stream>>>(curA, msg, rowstart, csr_col, csr_w, curB, acc, N);
        bf16* tmp = curA; curA = curB; curB = tmp;
    }
    k_out<<<(N + 63) / 64, 256, 0, stream>>>(acc, Wo_w, Wo_b, out, N);
}

// Round 3
// 1697.863 us; speedup vs baseline: 1.6549x; 1.6549x over previous
//
#include <hip/hip_runtime.h>
#include <hip/hip_bf16.h>

// GloAttnConv R3: wave-parallel k_kv (no barriers), MFMA k_attn on kvT(bf16),
// hoisted iteration-invariant denominator, wave-per-node k_gcn, LDS-W k_qk.

typedef __attribute__((ext_vector_type(8))) short bf16x8;
typedef __attribute__((ext_vector_type(4))) float f32x4v;

#define CHUNK 250   // k_kv chunk; graph boundaries (multiples of 1000) never split a chunk

__device__ __forceinline__ float asf(unsigned int u) { union { unsigned int i; float f; } v; v.i = u; return v.f; }
__device__ __forceinline__ float b2f_u(unsigned short u) { return asf((unsigned int)u << 16); }
__device__ __forceinline__ unsigned short f2b_u(float f) {
    __hip_bfloat16 h = __float2bfloat16(f);
    union { __hip_bfloat16 h; unsigned short u; } v; v.h = h; return v.u;
}
__device__ __forceinline__ unsigned int pack2(float a, float b) {
    return (unsigned int)f2b_u(a) | ((unsigned int)f2b_u(b) << 16);
}
__device__ __forceinline__ float wave_reduce_sum(float v) {
    #pragma unroll
    for (int off = 32; off > 0; off >>= 1) v += __shfl_xor(v, off, 64);
    return v;
}

// ---- graph bookkeeping -----------------------------------------------------
__global__ void k_ptr(const int* __restrict__ nn, int* __restrict__ ptr, int B) {
    if (threadIdx.x == 0 && blockIdx.x == 0) {
        int s = 0; ptr[0] = 0;
        for (int i = 0; i < B; ++i) { s += nn[i]; ptr[i + 1] = s; }
    }
}

__global__ void k_batch(const int* __restrict__ ptr, int* __restrict__ batch) {
    int b = blockIdx.x;
    int s = ptr[b], e = ptr[b + 1];
    for (int i = s + threadIdx.x; i < e; i += blockDim.x) batch[i] = b;
}

// ---- q/k projection + L2-normalize; init cur & acc. Wave-per-node. ---------
__global__ __launch_bounds__(256) void k_qk(
    const float* __restrict__ x,
    const float* __restrict__ Wq_w, const float* __restrict__ Wq_b,
    const float* __restrict__ Wk_w, const float* __restrict__ Wk_b,
    unsigned short* __restrict__ q, unsigned short* __restrict__ kq,
    unsigned short* __restrict__ curA, unsigned short* __restrict__ acc, int N)
{
    // ldsq[j][l] = float2(Wq[l][j], Wq[l+64][j]); same for k. 32 KB each.
    __shared__ float ldsq[64 * 128];
    __shared__ float ldsk[64 * 128];
    __shared__ float xs[4 * 64];
    int tid = threadIdx.x, w = tid >> 6, l = tid & 63;
    for (int idx = tid; idx < 8192; idx += 256) {
        int j = idx & 63, lc = idx >> 6, ll = lc & 63, half = lc >> 6;
        ldsq[(j * 64 + ll) * 2 + half] = Wq_w[((half << 6) + ll) * 64 + j];
        ldsk[(j * 64 + ll) * 2 + half] = Wk_w[((half << 6) + ll) * 64 + j];
    }
    float bq0 = Wq_b[l], bq1 = Wq_b[64 + l], bk0 = Wk_b[l], bk1 = Wk_b[64 + l];
    __syncthreads();
    const float2* lq = (const float2*)ldsq;
    const float2* lk = (const float2*)ldsk;
    for (int nb = blockIdx.x * 4; nb < N; nb += gridDim.x * 4) {
        int n = nb + w;
        __syncthreads();                       // xs reuse guard
        if (n < N) xs[w * 64 + l] = x[(size_t)n * 64 + l];
        __syncthreads();
        if (n >= N) continue;
        float q0 = bq0, q1 = bq1, k0 = bk0, k1 = bk1;
        #pragma unroll 8
        for (int j = 0; j < 64; ++j) {
            float xj = xs[w * 64 + j];         // LDS broadcast
            float2 wq = lq[j * 64 + l], wk = lk[j * 64 + l];
            q0 += xj * wq.x; q1 += xj * wq.y;
            k0 += xj * wk.x; k1 += xj * wk.y;
        }
        float sq0 = rsqrtf(wave_reduce_sum(q0 * q0));
        float sq1 = rsqrtf(wave_reduce_sum(q1 * q1));
        float sk0 = rsqrtf(wave_reduce_sum(k0 * k0));
        float sk1 = rsqrtf(wave_reduce_sum(k1 * k1));
        size_t o = (size_t)n * 128;
        q[o + l] = f2b_u(q0 * sq0);  q[o + 64 + l] = f2b_u(q1 * sq1);
        kq[o + l] = f2b_u(k0 * sk0); kq[o + 64 + l] = f2b_u(k1 * sk1);
        unsigned int pa = pack2(xs[w * 64 + ((2 * l) & 63)], xs[w * 64 + ((2 * l + 1) & 63)]);
        *(unsigned int*)(curA + o + 2 * l) = pa;
        *(unsigned int*)(acc + o + 2 * l) = pa;
    }
}

// ---- degree / dis ----------------------------------------------------------
__global__ void k_deg(const int* __restrict__ row, int* __restrict__ deg, int E) {
    int e = blockIdx.x * 256 + threadIdx.x;
    if (e < E) atomicAdd(&deg[row[e]], 1);
}

__global__ void k_dis(const int* __restrict__ deg, float* __restrict__ dis, int N) {
    int n = blockIdx.x * 256 + threadIdx.x;
    if (n < N) { int d = deg[n]; dis[n] = d > 0 ? rsqrtf((float)d) : 0.f; }
}

// ---- exclusive scan of deg -> rowstart -------------------------------------
__global__ void k_scan1(const int* __restrict__ deg, int* __restrict__ rowstart,
                        int* __restrict__ bsum, int N) {
    __shared__ int sh[256];
    int t = threadIdx.x, n = blockIdx.x * 256 + t;
    int v = (n < N) ? deg[n] : 0;
    sh[t] = v; __syncthreads();
    #pragma unroll
    for (int off = 1; off < 256; off <<= 1) {
        int add = (t >= off) ? sh[t - off] : 0;
        __syncthreads();
        sh[t] += add;
        __syncthreads();
    }
    if (n < N) rowstart[n] = sh[t] - v;
    if (t == 255) bsum[blockIdx.x] = sh[255];
}

__global__ void k_scan2(int* __restrict__ bsum, int nb) {
    __shared__ int sh[512];
    __shared__ int carry;
    int t = threadIdx.x;
    if (t == 0) carry = 0;
    __syncthreads();
    for (int base = 0; base < nb; base += 512) {
        int idx = base + t;
        int v = (idx < nb) ? bsum[idx] : 0;
        sh[t] = v; __syncthreads();
        for (int off = 1; off < 512; off <<= 1) {
            int add = (t >= off) ? sh[t - off] : 0;
            __syncthreads();
            sh[t] += add;
            __syncthreads();
        }
        if (idx < nb) bsum[idx] = sh[t] - v + carry;
        __syncthreads();
        if (t == 0) carry += sh[511];
        __syncthreads();
    }
}

__global__ void k_scan3(int* __restrict__ rowstart, const int* __restrict__ bsum, int N, int E) {
    int n = blockIdx.x * 256 + threadIdx.x;
    if (n < N) rowstart[n] += bsum[blockIdx.x];
    if (n == 0) rowstart[N] = E;
}

// ---- CSR fill --------------------------------------------------------------
__global__ void k_fill(const int* __restrict__ eidx, const float* __restrict__ dis,
                       const int* __restrict__ rowstart, int* __restrict__ cursor,
                       int* __restrict__ csr_col, float* __restrict__ csr_w,
                       int* __restrict__ csr_eid, int E) {
    int e = blockIdx.x * 256 + threadIdx.x;
    if (e >= E) return;
    int r = eidx[e], c = eidx[E + e];
    float wv = dis[r] * dis[c];
    int slot = atomicAdd(&cursor[r], 1);
    int idx = rowstart[r] + slot;
    csr_col[idx] = c; csr_w[idx] = wv; csr_eid[idx] = e;
}

// ---- msg_edge[n,64] --------------------------------------------------------
__global__ __launch_bounds__(64) void k_msg(
    const int* __restrict__ rowstart, const int* __restrict__ csr_eid,
    const float* __restrict__ csr_w, const int* __restrict__ eattr,
    const float* __restrict__ bond, float* __restrict__ msg, int N) {
    int n = blockIdx.x, t = threadIdx.x;
    int s0 = rowstart[n], s1 = rowstart[n + 1];
    float m = 0.f;
    for (int i = s0; i < s1; ++i) {
        int e = csr_eid[i];
        float wv = csr_w[i];
        int a0 = eattr[e * 3 + 0], a1 = eattr[e * 3 + 1], a2 = eattr[e * 3 + 2];
        m += wv * (bond[a0 * 64 + t] + bond[(8 + a1) * 64 + t] + bond[(16 + a2) * 64 + t]);
    }
    msg[n * 64 + t] = m;
}

// ---- k_sum per graph (iteration-invariant) ---------------------------------
__global__ __launch_bounds__(128) void k_ksum(
    const unsigned short* __restrict__ kq, const int* __restrict__ batch,
    float* __restrict__ ksum, int N) {
    int t = threadIdx.x;
    int start = blockIdx.x * 256;
    if (start >= N) return;
    int curb = batch[start];
    float a = 0.f;
    for (int i = 0; i < 256; ++i) {
        int n = start + i;
        if (n >= N) break;
        int b = batch[n];
        if (b != curb) { atomicAdd(&ksum[curb * 128 + t], a); a = 0.f; curb = b; }
        a += b2f_u(kq[(size_t)n * 128 + t]);
    }
    atomicAdd(&ksum[curb * 128 + t], a);
}

// ---- denom[n][h] = q[n,h,:].ksum[b,h,:] + n_nodes[b]  (iteration-invariant) -
__global__ __launch_bounds__(256) void k_denom(
    const unsigned short* __restrict__ q, const float* __restrict__ ksum,
    const int* __restrict__ batch, const int* __restrict__ nn,
    float* __restrict__ denom, int N)
{
    int w = threadIdx.x >> 6, l = threadIdx.x & 63;
    int n = blockIdx.x * 4 + w;
    if (n >= N) return;
    int b = batch[n];
    float d0 = b2f_u(q[(size_t)n * 128 + l]) * ksum[b * 128 + l];
    float d1 = b2f_u(q[(size_t)n * 128 + 64 + l]) * ksum[b * 128 + 64 + l];
    d0 = wave_reduce_sum(d0);
    d1 = wave_reduce_sum(d1);
    if (l == 0) {
        float nf = (float)nn[b];
        denom[n * 2 + 0] = d0 + nf;
        denom[n * 2 + 1] = d1 + nf;
    }
}

// ---- kvT[b,h,e,d] += sum_n v[n,h,e]*k[n,h,d]; vsum[b,h,e] ------------------
// Wave = (chunk, h, dhalf); lane owns 4(d) x 8(e) tile; no LDS, no barriers.
__global__ __launch_bounds__(256) void k_kv(
    const unsigned short* __restrict__ kq, const unsigned short* __restrict__ cur,
    const int* __restrict__ batch, float* __restrict__ kvT,
    float* __restrict__ vsum, int N)
{
    int w = threadIdx.x >> 6, l = threadIdx.x & 63;
    int h = w >> 1, dhalf = w & 1;
    int start = blockIdx.x * CHUNK;
    if (start >= N) return;
    int end = min(start + CHUNK, N);
    int d0 = dhalf * 32 + (l & 7) * 4;
    int e0 = (l >> 3) * 8;
    float a[4][8], va[8];
    #pragma unroll
    for (int i = 0; i < 4; ++i)
        #pragma unroll
        for (int j = 0; j < 8; ++j) a[i][j] = 0.f;
    #pragma unroll
    for (int j = 0; j < 8; ++j) va[j] = 0.f;

    int curb = batch[start];
    for (int n = start; n < end; ++n) {
        int b = batch[n];
        if (b != curb) {   // graph boundary (never hit for 250-aligned chunks here)
            float* dst = kvT + (size_t)(curb * 2 + h) * 4096;
            #pragma unroll
            for (int j = 0; j < 8; ++j)
                #pragma unroll
                for (int i = 0; i < 4; ++i) {
                    atomicAdd(&dst[(e0 + j) * 64 + d0 + i], a[i][j]);
                    a[i][j] = 0.f;
                }
            if (dhalf == 0 && (l & 7) == 0)
                #pragma unroll
                for (int j = 0; j < 8; ++j) {
                    atomicAdd(&vsum[(curb * 2 + h) * 64 + e0 + j], va[j]);
                    va[j] = 0.f;
                }
            curb = b;
        }
        const unsigned short* krow = kq + (size_t)n * 128 + h * 64;
        const unsigned short* vrow = cur + (size_t)n * 128 + h * 64;
        uint2 ku = *(const uint2*)(krow + d0);
        uint4 vu = *(const uint4*)(vrow + e0);
        float k0 = asf(ku.x << 16), k1 = asf(ku.x & 0xffff0000u);
        float k2 = asf(ku.y << 16), k3 = asf(ku.y & 0xffff0000u);
        float v[8];
        v[0] = asf(vu.x << 16); v[1] = asf(vu.x & 0xffff0000u);
        v[2] = asf(vu.y << 16); v[3] = asf(vu.y & 0xffff0000u);
        v[4] = asf(vu.z << 16); v[5] = asf(vu.z & 0xffff0000u);
        v[6] = asf(vu.w << 16); v[7] = asf(vu.w & 0xffff0000u);
        #pragma unroll
        for (int j = 0; j < 8; ++j) {
            a[0][j] += k0 * v[j]; a[1][j] += k1 * v[j];
            a[2][j] += k2 * v[j]; a[3][j] += k3 * v[j];
            va[j] += v[j];
        }
    }
    float* dst = kvT + (size_t)(curb * 2 + h) * 4096;
    #pragma unroll
    for (int j = 0; j < 8; ++j)
        #pragma unroll
        for (int i = 0; i < 4; ++i)
            atomicAdd(&dst[(e0 + j) * 64 + d0 + i], a[i][j]);
    if (dhalf == 0 && (l & 7) == 0)
        #pragma unroll
        for (int j = 0; j < 8; ++j)
            atomicAdd(&vsum[(curb * 2 + h) * 64 + e0 + j], va[j]);
}

// ---- kvT fp32 -> bf16 (linear) ---------------------------------------------
__global__ void k_cvt(const float* __restrict__ src, unsigned short* __restrict__ dst, int n4) {
    int i = blockIdx.x * 256 + threadIdx.x;
    if (i >= n4) return;
    float4 v = ((const float4*)src)[i];
    ushort4 o;
    o.x = f2b_u(v.x); o.y = f2b_u(v.y); o.z = f2b_u(v.z); o.w = f2b_u(v.w);
    ((ushort4*)dst)[i] = o;
}

// ---- attn via MFMA: num[n,h,e] = sum_d q[n,h,d]*kvT[b,h,e,d]; write 0.5*attn
__global__ __launch_bounds__(256) void k_attn(
    const unsigned short* __restrict__ q, const unsigned short* __restrict__ kvT,
    const float* __restrict__ vsum, const float* __restrict__ denom,
    const int* __restrict__ batch, unsigned short* __restrict__ curB, int N)
{
    int w = threadIdx.x >> 6, l = threadIdx.x & 63;
    int base = blockIdx.x * 64 + w * 16;
    if (base >= N) return;
    int quad = l >> 4, six = l & 15;
    int b0 = batch[base];
    int nlast = min(base + 15, N - 1);
    bool uni = (base + 15 < N) && (batch[nlast] == b0);
    if (uni) {
        int n = base + six;   // A-row m = lane&15
        #pragma unroll
        for (int h = 0; h < 2; ++h) {
            const unsigned short* qrow = q + (size_t)n * 128 + h * 64;
            bf16x8 a0 = *(const bf16x8*)(qrow + quad * 8);        // k = quad*8+j
            bf16x8 a1 = *(const bf16x8*)(qrow + 32 + quad * 8);   // k = 32+quad*8+j
            const unsigned short* Bb = kvT + (size_t)(b0 * 2 + h) * 4096;
            f32x4v acc[4];
            #pragma unroll
            for (int et = 0; et < 4; ++et) {
                const unsigned short* brow = Bb + (size_t)(et * 16 + six) * 64; // col = lane&15
                bf16x8 bb0 = *(const bf16x8*)(brow + quad * 8);
                bf16x8 bb1 = *(const bf16x8*)(brow + 32 + quad * 8);
                f32x4v c = {0.f, 0.f, 0.f, 0.f};
                c = __builtin_amdgcn_mfma_f32_16x16x32_bf16(a0, bb0, c, 0, 0, 0);
                c = __builtin_amdgcn_mfma_f32_16x16x32_bf16(a1, bb1, c, 0, 0, 0);
                acc[et] = c;
            }
            #pragma unroll
            for (int et = 0; et < 4; ++et) {
                int e = et * 16 + six;
                float vs = vsum[(b0 * 2 + h) * 64 + e];
                #pragma unroll
                for (int r = 0; r < 4; ++r) {
                    int nr = base + quad * 4 + r;                 // C row = quad*4+reg
                    float dn = denom[nr * 2 + h];
                    float val = 0.5f * (acc[et][r] + vs) / dn;
                    curB[(size_t)nr * 128 + h * 64 + e] = f2b_u(val);
                }
            }
        }
    } else {
        // slow path (graph boundary inside tile or tail): lanes = e
        for (int i = 0; i < 16; ++i) {
            int n = base + i;
            if (n >= N) break;
            int b = batch[n];
            #pragma unroll
            for (int h = 0; h < 2; ++h) {
                float num = 0.f;
                const unsigned short* krow = kvT + (size_t)((b * 2 + h) * 64 + l) * 64;
                for (int d = 0; d < 64; ++d)
                    num += b2f_u(q[(size_t)n * 128 + h * 64 + d]) * b2f_u(krow[d]);
                float val = 0.5f * (num + vsum[(b * 2 + h) * 64 + l]) / denom[n * 2 + h];
                curB[(size_t)n * 128 + h * 64 + l] = f2b_u(val);
            }
        }
    }
}

// ---- GCN gather + combine (wave per node) ----------------------------------
__global__ __launch_bounds__(256) void k_gcn(
    const unsigned short* __restrict__ curA, const float* __restrict__ msg,
    const int* __restrict__ rowstart, const int* __restrict__ csr_col,
    const float* __restrict__ csr_w,
    unsigned short* __restrict__ curB, unsigned short* __restrict__ acc, int N)
{
    int w = threadIdx.x >> 6, l = threadIdx.x & 63;
    int n = blockIdx.x * 4 + w;
    if (n >= N) return;
    int s0 = rowstart[n], s1 = rowstart[n + 1];
    float g0 = 0.f, g1 = 0.f;
    #pragma unroll 2
    for (int i = s0; i < s1; ++i) {
        int c = csr_col[i];
        float wv = csr_w[i];
        unsigned int u = *(const unsigned int*)(curA + (size_t)c * 128 + 2 * l);
        g0 += wv * asf(u << 16);
        g1 += wv * asf(u & 0xffff0000u);
    }
    float2 m = *(const float2*)(msg + (size_t)n * 64 + ((2 * l) & 63));
    size_t o = (size_t)n * 128 + 2 * l;
    unsigned int ub = *(const unsigned int*)(curB + o);
    float v0 = 0.5f * (g0 + m.x) + asf(ub << 16);
    float v1 = 0.5f * (g1 + m.y) + asf(ub & 0xffff0000u);
    *(unsigned int*)(curB + o) = pack2(v0, v1);
    unsigned int ua = *(const unsigned int*)(acc + o);
    *(unsigned int*)(acc + o) = pack2(asf(ua << 16) + v0, asf(ua & 0xffff0000u) + v1);
}

// ---- out = (acc @ Wo^T + b) / 2 -------------------------------------------
__global__ __launch_bounds__(256) void k_out(
    const unsigned short* __restrict__ acc, const float* __restrict__ Wo_w,
    const float* __restrict__ Wo_b, float* __restrict__ out, int N)
{
    __shared__ float wol[64 * 129];
    __shared__ float accl[512];
    int t = threadIdx.x;
    for (int idx = t; idx < 64 * 128; idx += 256) {
        int o = idx >> 7, c = idx & 127;
        wol[o * 129 + c] = Wo_w[idx];
    }
    float bias = Wo_b[t & 63];
    __syncthreads();
    int base = blockIdx.x * 64;
    for (int s = 0; s < 16; ++s) {
        int nb = base + s * 4;
        __syncthreads();
        for (int idx = t; idx < 512; idx += 256) {
            int r = idx >> 7, c = idx & 127;
            int n = nb + r;
            accl[idx] = (n < N) ? b2f_u(acc[(size_t)n * 128 + c]) : 0.f;
        }
        __syncthreads();
        int i = t >> 6, o = t & 63;
        int n = nb + i;
        if (n < N) {
            float s2 = 0.f;
            const float4* a4 = (const float4*)(accl + i * 128);
            #pragma unroll
            for (int c4 = 0; c4 < 32; ++c4) {
                float4 av = a4[c4];
                s2 += av.x * wol[o * 129 + c4 * 4 + 0] + av.y * wol[o * 129 + c4 * 4 + 1]
                    + av.z * wol[o * 129 + c4 * 4 + 2] + av.w * wol[o * 129 + c4 * 4 + 3];
            }
            out[n * 64 + o] = (s2 + bias) * 0.5f;
        }
    }
}

extern "C" void kernel_launch(void* const* d_in, const int* in_sizes, int n_in,
                              void* d_out, int out_size, void* d_ws, size_t ws_size,
                              hipStream_t stream) {
    const float* x    = (const float*)d_in[0];
    const float* Wq_w = (const float*)d_in[1];
    const float* Wq_b = (const float*)d_in[2];
    const float* Wk_w = (const float*)d_in[3];
    const float* Wk_b = (const float*)d_in[4];
    const float* Wo_w = (const float*)d_in[5];
    const float* Wo_b = (const float*)d_in[6];
    const float* bond = (const float*)d_in[7];
    const int*   eidx = (const int*)d_in[8];
    const int*   eattr= (const int*)d_in[9];
    const int*   nn   = (const int*)d_in[10];
    float* out = (float*)d_out;
    int N = in_sizes[0] / 64;
    int E = in_sizes[9] / 3;
    int B = in_sizes[10];

    char* p = (char*)d_ws;
    auto alloc = [&](size_t bytes) { char* r = p; p += (bytes + 255) & ~(size_t)255; return r; };
    unsigned short* q    = (unsigned short*)alloc((size_t)N * 128 * 2);
    unsigned short* kq   = (unsigned short*)alloc((size_t)N * 128 * 2);
    unsigned short* curA = (unsigned short*)alloc((size_t)N * 128 * 2);
    unsigned short* curB = (unsigned short*)alloc((size_t)N * 128 * 2);
    unsigned short* acc  = (unsigned short*)alloc((size_t)N * 128 * 2);
    // kvT_f32 and vsum contiguous -> one memset
    float* kvT_f = (float*)alloc((size_t)B * 2 * 64 * 64 * 4);
    float* vsum  = (float*)alloc((size_t)B * 128 * 4);
    unsigned short* kvT_b = (unsigned short*)alloc((size_t)B * 2 * 64 * 64 * 2);
    float* ksum  = (float*)alloc((size_t)B * 128 * 4);
    float* denom = (float*)alloc((size_t)N * 2 * 4);
    float* dis   = (float*)alloc((size_t)N * 4);
    int* deg     = (int*)alloc((size_t)N * 4);
    int* rowstart= (int*)alloc((size_t)(N + 1) * 4);
    int* cursor  = (int*)alloc((size_t)N * 4);
    int* csr_col = (int*)alloc((size_t)E * 4);
    float* csr_w = (float*)alloc((size_t)E * 4);
    int* csr_eid = (int*)alloc((size_t)E * 4);
    int* batch   = (int*)alloc((size_t)N * 4);
    int* ptr     = (int*)alloc((size_t)(B + 1) * 4);
    int nb = (N + 255) / 256;
    int* bsum    = (int*)alloc((size_t)nb * 4);
    float* msg   = out;   // [N,64] fp32 aliased onto d_out; k_out rewrites it last

    size_t kvreg = (size_t)B * 2 * 64 * 64 * 4 + (size_t)B * 128 * 4;

    hipMemsetAsync(deg,    0, (size_t)N * 4, stream);
    hipMemsetAsync(cursor, 0, (size_t)N * 4, stream);
    hipMemsetAsync(ksum,   0, (size_t)B * 128 * 4, stream);

    k_ptr  <<<1, 64, 0, stream>>>(nn, ptr, B);
    k_batch<<<B, 256, 0, stream>>>(ptr, batch);
    k_qk   <<<256, 256, 0, stream>>>(x, Wq_w, Wq_b, Wk_w, Wk_b, q, kq, curA, acc, N);
    k_deg  <<<(E + 255) / 256, 256, 0, stream>>>(eidx, deg, E);
    k_dis  <<<(N + 255) / 256, 256, 0, stream>>>(deg, dis, N);
    k_scan1<<<nb, 256, 0, stream>>>(deg, rowstart, bsum, N);
    k_scan2<<<1, 512, 0, stream>>>(bsum, nb);
    k_scan3<<<nb, 256, 0, stream>>>(rowstart, bsum, N, E);
    k_fill <<<(E + 255) / 256, 256, 0, stream>>>(eidx, dis, rowstart, cursor, csr_col, csr_w, csr_eid, E);
    k_msg  <<<N, 64, 0, stream>>>(rowstart, csr_eid, csr_w, eattr, bond, msg, N);
    k_ksum <<<(N + 255) / 256, 128, 0, stream>>>(kq, batch, ksum, N);
    k_denom<<<(N + 3) / 4, 256, 0, stream>>>(q, ksum, batch, nn, denom, N);

    int kvblocks = (N + CHUNK - 1) / CHUNK;
    int n4 = B * 2 * 64 * 64 / 4;
    for (int it = 0; it < 4; ++it) {
        hipMemsetAsync(kvT_f, 0, kvreg, stream);
        k_kv  <<<kvblocks, 256, 0, stream>>>(kq, curA, batch, kvT_f, vsum, N);
        k_cvt <<<(n4 + 255) / 256, 256, 0, stream>>>(kvT_f, kvT_b, n4);
        k_attn<<<(N + 63) / 64, 256, 0, stream>>>(q, kvT_b, vsum, denom, batch, curB, N);
        k_gcn <<<(N + 3) / 4, 256, 0, stream>>>(curA, msg, rowstart, csr_col, csr_w, curB, acc, N);
        unsigned short* tmp = curA; curA = curB; curB = tmp;
    }
    k_out<<<(N + 63) / 64, 256, 0, stream>>>(acc, Wo_w, Wo_b, out, N);
}

// Round 4
// 1568.155 us; speedup vs baseline: 1.7917x; 1.0827x over previous
//
#include <hip/hip_runtime.h>
#include <hip/hip_bf16.h>

// GloAttnConv R4: k_qk rewritten thread-per-output-col (W in VGPRs, broadcast x,
// no big LDS, no bank conflicts); k_msg uses packed csr_att + LDS bond table.

typedef __attribute__((ext_vector_type(8))) short bf16x8;
typedef __attribute__((ext_vector_type(4))) float f32x4v;

#define CHUNK 250   // k_kv chunk; graph boundaries (multiples of 1000) never split a chunk

__device__ __forceinline__ float asf(unsigned int u) { union { unsigned int i; float f; } v; v.i = u; return v.f; }
__device__ __forceinline__ float b2f_u(unsigned short u) { return asf((unsigned int)u << 16); }
__device__ __forceinline__ unsigned short f2b_u(float f) {
    __hip_bfloat16 h = __float2bfloat16(f);
    union { __hip_bfloat16 h; unsigned short u; } v; v.h = h; return v.u;
}
__device__ __forceinline__ unsigned int pack2(float a, float b) {
    return (unsigned int)f2b_u(a) | ((unsigned int)f2b_u(b) << 16);
}
__device__ __forceinline__ float wave_reduce_sum(float v) {
    #pragma unroll
    for (int off = 32; off > 0; off >>= 1) v += __shfl_xor(v, off, 64);
    return v;
}

// ---- graph bookkeeping -----------------------------------------------------
__global__ void k_ptr(const int* __restrict__ nn, int* __restrict__ ptr, int B) {
    if (threadIdx.x == 0 && blockIdx.x == 0) {
        int s = 0; ptr[0] = 0;
        for (int i = 0; i < B; ++i) { s += nn[i]; ptr[i + 1] = s; }
    }
}

__global__ void k_batch(const int* __restrict__ ptr, int* __restrict__ batch) {
    int b = blockIdx.x;
    int s = ptr[b], e = ptr[b + 1];
    for (int i = s + threadIdx.x; i < e; i += blockDim.x) batch[i] = b;
}

// ---- q/k projection + L2-normalize; init cur & acc. Thread = output col. ----
// wave 0: q head0, wave 1: q head1, wave 2: k head0, wave 3: k head1.
__global__ __launch_bounds__(256) void k_qk(
    const float* __restrict__ x,
    const float* __restrict__ Wq_w, const float* __restrict__ Wq_b,
    const float* __restrict__ Wk_w, const float* __restrict__ Wk_b,
    unsigned short* __restrict__ q, unsigned short* __restrict__ kq,
    unsigned short* __restrict__ curA, unsigned short* __restrict__ acc, int N)
{
    int t = threadIdx.x, w = t >> 6, l = t & 63;
    int col = ((w & 1) << 6) | l;           // 0..127 within q or k
    const float* W = (w >= 2) ? Wk_w : Wq_w;
    float4 wr[16];
    {
        const float4* Wrow = (const float4*)(W + col * 64);
        #pragma unroll
        for (int j = 0; j < 16; ++j) wr[j] = Wrow[j];
    }
    float bias = (w >= 2) ? Wk_b[col] : Wq_b[col];
    unsigned short* dst = (w >= 2) ? kq : q;

    __shared__ float xs[2][64];
    for (int n0 = blockIdx.x * 2; n0 < N; n0 += gridDim.x * 2) {
        __syncthreads();
        if (t < 128) {
            int nx = n0 + (t >> 6);
            xs[t >> 6][t & 63] = (nx < N) ? x[(size_t)nx * 64 + (t & 63)] : 0.f;
        }
        __syncthreads();
        #pragma unroll
        for (int s = 0; s < 2; ++s) {
            int n = n0 + s;
            if (n >= N) continue;
            const float4* xv = (const float4*)xs[s];
            float a0 = 0.f, a1 = 0.f, a2 = 0.f, a3 = 0.f;
            #pragma unroll
            for (int j = 0; j < 4; ++j) {
                float4 x0 = xv[j * 4 + 0], x1 = xv[j * 4 + 1];
                float4 x2 = xv[j * 4 + 2], x3 = xv[j * 4 + 3];
                float4 w0 = wr[j * 4 + 0], w1 = wr[j * 4 + 1];
                float4 w2 = wr[j * 4 + 2], w3 = wr[j * 4 + 3];
                a0 += x0.x * w0.x + x0.y * w0.y + x0.z * w0.z + x0.w * w0.w;
                a1 += x1.x * w1.x + x1.y * w1.y + x1.z * w1.z + x1.w * w1.w;
                a2 += x2.x * w2.x + x2.y * w2.y + x2.z * w2.z + x2.w * w2.w;
                a3 += x3.x * w3.x + x3.y * w3.y + x3.z * w3.z + x3.w * w3.w;
            }
            float v = a0 + a1 + a2 + a3 + bias;
            float ss = wave_reduce_sum(v * v);
            float o = v * rsqrtf(ss);
            dst[(size_t)n * 128 + col] = f2b_u(o);
        }
        // curA/acc init: 256 threads cover 2 nodes x 128 cols (c&63 == l)
        {
            int nx = n0 + (w >> 1);
            if (nx < N) {
                unsigned short pb = f2b_u(xs[w >> 1][l]);
                size_t o = (size_t)nx * 128 + col;
                curA[o] = pb;
                acc[o] = pb;
            }
        }
    }
}

// ---- degree / dis ----------------------------------------------------------
__global__ void k_deg(const int* __restrict__ row, int* __restrict__ deg, int E) {
    int e = blockIdx.x * 256 + threadIdx.x;
    if (e < E) atomicAdd(&deg[row[e]], 1);
}

__global__ void k_dis(const int* __restrict__ deg, float* __restrict__ dis, int N) {
    int n = blockIdx.x * 256 + threadIdx.x;
    if (n < N) { int d = deg[n]; dis[n] = d > 0 ? rsqrtf((float)d) : 0.f; }
}

// ---- exclusive scan of deg -> rowstart -------------------------------------
__global__ void k_scan1(const int* __restrict__ deg, int* __restrict__ rowstart,
                        int* __restrict__ bsum, int N) {
    __shared__ int sh[256];
    int t = threadIdx.x, n = blockIdx.x * 256 + t;
    int v = (n < N) ? deg[n] : 0;
    sh[t] = v; __syncthreads();
    #pragma unroll
    for (int off = 1; off < 256; off <<= 1) {
        int add = (t >= off) ? sh[t - off] : 0;
        __syncthreads();
        sh[t] += add;
        __syncthreads();
    }
    if (n < N) rowstart[n] = sh[t] - v;
    if (t == 255) bsum[blockIdx.x] = sh[255];
}

__global__ void k_scan2(int* __restrict__ bsum, int nb) {
    __shared__ int sh[512];
    __shared__ int carry;
    int t = threadIdx.x;
    if (t == 0) carry = 0;
    __syncthreads();
    for (int base = 0; base < nb; base += 512) {
        int idx = base + t;
        int v = (idx < nb) ? bsum[idx] : 0;
        sh[t] = v; __syncthreads();
        for (int off = 1; off < 512; off <<= 1) {
            int add = (t >= off) ? sh[t - off] : 0;
            __syncthreads();
            sh[t] += add;
            __syncthreads();
        }
        if (idx < nb) bsum[idx] = sh[t] - v + carry;
        __syncthreads();
        if (t == 0) carry += sh[511];
        __syncthreads();
    }
}

__global__ void k_scan3(int* __restrict__ rowstart, const int* __restrict__ bsum, int N, int E) {
    int n = blockIdx.x * 256 + threadIdx.x;
    if (n < N) rowstart[n] += bsum[blockIdx.x];
    if (n == 0) rowstart[N] = E;
}

// ---- CSR fill (also packs edge attributes) ---------------------------------
__global__ void k_fill(const int* __restrict__ eidx, const float* __restrict__ dis,
                       const int* __restrict__ rowstart, int* __restrict__ cursor,
                       int* __restrict__ csr_col, float* __restrict__ csr_w,
                       int* __restrict__ csr_att, const int* __restrict__ eattr, int E) {
    int e = blockIdx.x * 256 + threadIdx.x;
    if (e >= E) return;
    int r = eidx[e], c = eidx[E + e];
    float wv = dis[r] * dis[c];
    int a0 = eattr[e * 3 + 0], a1 = eattr[e * 3 + 1], a2 = eattr[e * 3 + 2];
    int slot = atomicAdd(&cursor[r], 1);
    int idx = rowstart[r] + slot;
    csr_col[idx] = c; csr_w[idx] = wv; csr_att[idx] = a0 | (a1 << 8) | (a2 << 16);
}

// ---- msg_edge[n,64]; bond table in LDS, wave per node ----------------------
__global__ __launch_bounds__(256) void k_msg(
    const int* __restrict__ rowstart, const int* __restrict__ csr_att,
    const float* __restrict__ csr_w, const float* __restrict__ bond,
    float* __restrict__ msg, int N) {
    __shared__ float bl[1536];
    int t = threadIdx.x, w = t >> 6, l = t & 63;
    for (int i = t; i < 1536; i += 256) bl[i] = bond[i];
    __syncthreads();
    for (int n = blockIdx.x * 4 + w; n < N; n += gridDim.x * 4) {
        int s0 = rowstart[n], s1 = rowstart[n + 1];
        float m = 0.f;
        for (int i = s0; i < s1; ++i) {
            int att = csr_att[i];
            float wv = csr_w[i];
            m += wv * (bl[(att & 255) * 64 + l] + bl[(8 + ((att >> 8) & 255)) * 64 + l]
                     + bl[(16 + (att >> 16)) * 64 + l]);
        }
        msg[(size_t)n * 64 + l] = m;
    }
}

// ---- k_sum per graph (iteration-invariant) ---------------------------------
__global__ __launch_bounds__(128) void k_ksum(
    const unsigned short* __restrict__ kq, const int* __restrict__ batch,
    float* __restrict__ ksum, int N) {
    int t = threadIdx.x;
    int start = blockIdx.x * 256;
    if (start >= N) return;
    int curb = batch[start];
    float a = 0.f;
    for (int i = 0; i < 256; ++i) {
        int n = start + i;
        if (n >= N) break;
        int b = batch[n];
        if (b != curb) { atomicAdd(&ksum[curb * 128 + t], a); a = 0.f; curb = b; }
        a += b2f_u(kq[(size_t)n * 128 + t]);
    }
    atomicAdd(&ksum[curb * 128 + t], a);
}

// ---- denom[n][h] = q[n,h,:].ksum[b,h,:] + n_nodes[b]  (iteration-invariant) -
__global__ __launch_bounds__(256) void k_denom(
    const unsigned short* __restrict__ q, const float* __restrict__ ksum,
    const int* __restrict__ batch, const int* __restrict__ nn,
    float* __restrict__ denom, int N)
{
    int w = threadIdx.x >> 6, l = threadIdx.x & 63;
    int n = blockIdx.x * 4 + w;
    if (n >= N) return;
    int b = batch[n];
    float d0 = b2f_u(q[(size_t)n * 128 + l]) * ksum[b * 128 + l];
    float d1 = b2f_u(q[(size_t)n * 128 + 64 + l]) * ksum[b * 128 + 64 + l];
    d0 = wave_reduce_sum(d0);
    d1 = wave_reduce_sum(d1);
    if (l == 0) {
        float nf = (float)nn[b];
        denom[n * 2 + 0] = d0 + nf;
        denom[n * 2 + 1] = d1 + nf;
    }
}

// ---- kvT[b,h,e,d] += sum_n v[n,h,e]*k[n,h,d]; vsum[b,h,e] ------------------
__global__ __launch_bounds__(256) void k_kv(
    const unsigned short* __restrict__ kq, const unsigned short* __restrict__ cur,
    const int* __restrict__ batch, float* __restrict__ kvT,
    float* __restrict__ vsum, int N)
{
    int w = threadIdx.x >> 6, l = threadIdx.x & 63;
    int h = w >> 1, dhalf = w & 1;
    int start = blockIdx.x * CHUNK;
    if (start >= N) return;
    int end = min(start + CHUNK, N);
    int d0 = dhalf * 32 + (l & 7) * 4;
    int e0 = (l >> 3) * 8;
    float a[4][8], va[8];
    #pragma unroll
    for (int i = 0; i < 4; ++i)
        #pragma unroll
        for (int j = 0; j < 8; ++j) a[i][j] = 0.f;
    #pragma unroll
    for (int j = 0; j < 8; ++j) va[j] = 0.f;

    int curb = batch[start];
    for (int n = start; n < end; ++n) {
        int b = batch[n];
        if (b != curb) {
            float* dst = kvT + (size_t)(curb * 2 + h) * 4096;
            #pragma unroll
            for (int j = 0; j < 8; ++j)
                #pragma unroll
                for (int i = 0; i < 4; ++i) {
                    atomicAdd(&dst[(e0 + j) * 64 + d0 + i], a[i][j]);
                    a[i][j] = 0.f;
                }
            if (dhalf == 0 && (l & 7) == 0)
                #pragma unroll
                for (int j = 0; j < 8; ++j) {
                    atomicAdd(&vsum[(curb * 2 + h) * 64 + e0 + j], va[j]);
                    va[j] = 0.f;
                }
            curb = b;
        }
        const unsigned short* krow = kq + (size_t)n * 128 + h * 64;
        const unsigned short* vrow = cur + (size_t)n * 128 + h * 64;
        uint2 ku = *(const uint2*)(krow + d0);
        uint4 vu = *(const uint4*)(vrow + e0);
        float k0 = asf(ku.x << 16), k1 = asf(ku.x & 0xffff0000u);
        float k2 = asf(ku.y << 16), k3 = asf(ku.y & 0xffff0000u);
        float v[8];
        v[0] = asf(vu.x << 16); v[1] = asf(vu.x & 0xffff0000u);
        v[2] = asf(vu.y << 16); v[3] = asf(vu.y & 0xffff0000u);
        v[4] = asf(vu.z << 16); v[5] = asf(vu.z & 0xffff0000u);
        v[6] = asf(vu.w << 16); v[7] = asf(vu.w & 0xffff0000u);
        #pragma unroll
        for (int j = 0; j < 8; ++j) {
            a[0][j] += k0 * v[j]; a[1][j] += k1 * v[j];
            a[2][j] += k2 * v[j]; a[3][j] += k3 * v[j];
            va[j] += v[j];
        }
    }
    float* dst = kvT + (size_t)(curb * 2 + h) * 4096;
    #pragma unroll
    for (int j = 0; j < 8; ++j)
        #pragma unroll
        for (int i = 0; i < 4; ++i)
            atomicAdd(&dst[(e0 + j) * 64 + d0 + i], a[i][j]);
    if (dhalf == 0 && (l & 7) == 0)
        #pragma unroll
        for (int j = 0; j < 8; ++j)
            atomicAdd(&vsum[(curb * 2 + h) * 64 + e0 + j], va[j]);
}

// ---- kvT fp32 -> bf16 (linear) ---------------------------------------------
__global__ void k_cvt(const float* __restrict__ src, unsigned short* __restrict__ dst, int n4) {
    int i = blockIdx.x * 256 + threadIdx.x;
    if (i >= n4) return;
    float4 v = ((const float4*)src)[i];
    ushort4 o;
    o.x = f2b_u(v.x); o.y = f2b_u(v.y); o.z = f2b_u(v.z); o.w = f2b_u(v.w);
    ((ushort4*)dst)[i] = o;
}

// ---- attn via MFMA: num[n,h,e] = sum_d q[n,h,d]*kvT[b,h,e,d]; write 0.5*attn
__global__ __launch_bounds__(256) void k_attn(
    const unsigned short* __restrict__ q, const unsigned short* __restrict__ kvT,
    const float* __restrict__ vsum, const float* __restrict__ denom,
    const int* __restrict__ batch, unsigned short* __restrict__ curB, int N)
{
    int w = threadIdx.x >> 6, l = threadIdx.x & 63;
    int base = blockIdx.x * 64 + w * 16;
    if (base >= N) return;
    int quad = l >> 4, six = l & 15;
    int b0 = batch[base];
    int nlast = min(base + 15, N - 1);
    bool uni = (base + 15 < N) && (batch[nlast] == b0);
    if (uni) {
        int n = base + six;
        #pragma unroll
        for (int h = 0; h < 2; ++h) {
            const unsigned short* qrow = q + (size_t)n * 128 + h * 64;
            bf16x8 a0 = *(const bf16x8*)(qrow + quad * 8);
            bf16x8 a1 = *(const bf16x8*)(qrow + 32 + quad * 8);
            const unsigned short* Bb = kvT + (size_t)(b0 * 2 + h) * 4096;
            f32x4v acc[4];
            #pragma unroll
            for (int et = 0; et < 4; ++et) {
                const unsigned short* brow = Bb + (size_t)(et * 16 + six) * 64;
                bf16x8 bb0 = *(const bf16x8*)(brow + quad * 8);
                bf16x8 bb1 = *(const bf16x8*)(brow + 32 + quad * 8);
                f32x4v c = {0.f, 0.f, 0.f, 0.f};
                c = __builtin_amdgcn_mfma_f32_16x16x32_bf16(a0, bb0, c, 0, 0, 0);
                c = __builtin_amdgcn_mfma_f32_16x16x32_bf16(a1, bb1, c, 0, 0, 0);
                acc[et] = c;
            }
            #pragma unroll
            for (int et = 0; et < 4; ++et) {
                int e = et * 16 + six;
                float vs = vsum[(b0 * 2 + h) * 64 + e];
                #pragma unroll
                for (int r = 0; r < 4; ++r) {
                    int nr = base + quad * 4 + r;
                    float dn = denom[nr * 2 + h];
                    float val = 0.5f * (acc[et][r] + vs) / dn;
                    curB[(size_t)nr * 128 + h * 64 + e] = f2b_u(val);
                }
            }
        }
    } else {
        for (int i = 0; i < 16; ++i) {
            int n = base + i;
            if (n >= N) break;
            int b = batch[n];
            #pragma unroll
            for (int h = 0; h < 2; ++h) {
                float num = 0.f;
                const unsigned short* krow = kvT + (size_t)((b * 2 + h) * 64 + l) * 64;
                for (int d = 0; d < 64; ++d)
                    num += b2f_u(q[(size_t)n * 128 + h * 64 + d]) * b2f_u(krow[d]);
                float val = 0.5f * (num + vsum[(b * 2 + h) * 64 + l]) / denom[n * 2 + h];
                curB[(size_t)n * 128 + h * 64 + l] = f2b_u(val);
            }
        }
    }
}

// ---- GCN gather + combine (wave per node) ----------------------------------
__global__ __launch_bounds__(256) void k_gcn(
    const unsigned short* __restrict__ curA, const float* __restrict__ msg,
    const int* __restrict__ rowstart, const int* __restrict__ csr_col,
    const float* __restrict__ csr_w,
    unsigned short* __restrict__ curB, unsigned short* __restrict__ acc, int N)
{
    int w = threadIdx.x >> 6, l = threadIdx.x & 63;
    int n = blockIdx.x * 4 + w;
    if (n >= N) return;
    int s0 = rowstart[n], s1 = rowstart[n + 1];
    float g0 = 0.f, g1 = 0.f;
    #pragma unroll 2
    for (int i = s0; i < s1; ++i) {
        int c = csr_col[i];
        float wv = csr_w[i];
        unsigned int u = *(const unsigned int*)(curA + (size_t)c * 128 + 2 * l);
        g0 += wv * asf(u << 16);
        g1 += wv * asf(u & 0xffff0000u);
    }
    float2 m = *(const float2*)(msg + (size_t)n * 64 + ((2 * l) & 63));
    size_t o = (size_t)n * 128 + 2 * l;
    unsigned int ub = *(const unsigned int*)(curB + o);
    float v0 = 0.5f * (g0 + m.x) + asf(ub << 16);
    float v1 = 0.5f * (g1 + m.y) + asf(ub & 0xffff0000u);
    *(unsigned int*)(curB + o) = pack2(v0, v1);
    unsigned int ua = *(const unsigned int*)(acc + o);
    *(unsigned int*)(acc + o) = pack2(asf(ua << 16) + v0, asf(ua & 0xffff0000u) + v1);
}

// ---- out = (acc @ Wo^T + b) / 2 -------------------------------------------
__global__ __launch_bounds__(256) void k_out(
    const unsigned short* __restrict__ acc, const float* __restrict__ Wo_w,
    const float* __restrict__ Wo_b, float* __restrict__ out, int N)
{
    __shared__ float wol[64 * 129];
    __shared__ float accl[512];
    int t = threadIdx.x;
    for (int idx = t; idx < 64 * 128; idx += 256) {
        int o = idx >> 7, c = idx & 127;
        wol[o * 129 + c] = Wo_w[idx];
    }
    float bias = Wo_b[t & 63];
    __syncthreads();
    int base = blockIdx.x * 64;
    for (int s = 0; s < 16; ++s) {
        int nb = base + s * 4;
        __syncthreads();
        for (int idx = t; idx < 512; idx += 256) {
            int r = idx >> 7, c = idx & 127;
            int n = nb + r;
            accl[idx] = (n < N) ? b2f_u(acc[(size_t)n * 128 + c]) : 0.f;
        }
        __syncthreads();
        int i = t >> 6, o = t & 63;
        int n = nb + i;
        if (n < N) {
            float s2 = 0.f;
            const float4* a4 = (const float4*)(accl + i * 128);
            #pragma unroll
            for (int c4 = 0; c4 < 32; ++c4) {
                float4 av = a4[c4];
                s2 += av.x * wol[o * 129 + c4 * 4 + 0] + av.y * wol[o * 129 + c4 * 4 + 1]
                    + av.z * wol[o * 129 + c4 * 4 + 2] + av.w * wol[o * 129 + c4 * 4 + 3];
            }
            out[n * 64 + o] = (s2 + bias) * 0.5f;
        }
    }
}

extern "C" void kernel_launch(void* const* d_in, const int* in_sizes, int n_in,
                              void* d_out, int out_size, void* d_ws, size_t ws_size,
                              hipStream_t stream) {
    const float* x    = (const float*)d_in[0];
    const float* Wq_w = (const float*)d_in[1];
    const float* Wq_b = (const float*)d_in[2];
    const float* Wk_w = (const float*)d_in[3];
    const float* Wk_b = (const float*)d_in[4];
    const float* Wo_w = (const float*)d_in[5];
    const float* Wo_b = (const float*)d_in[6];
    const float* bond = (const float*)d_in[7];
    const int*   eidx = (const int*)d_in[8];
    const int*   eattr= (const int*)d_in[9];
    const int*   nn   = (const int*)d_in[10];
    float* out = (float*)d_out;
    int N = in_sizes[0] / 64;
    int E = in_sizes[9] / 3;
    int B = in_sizes[10];

    char* p = (char*)d_ws;
    auto alloc = [&](size_t bytes) { char* r = p; p += (bytes + 255) & ~(size_t)255; return r; };
    unsigned short* q    = (unsigned short*)alloc((size_t)N * 128 * 2);
    unsigned short* kq   = (unsigned short*)alloc((size_t)N * 128 * 2);
    unsigned short* curA = (unsigned short*)alloc((size_t)N * 128 * 2);
    unsigned short* curB = (unsigned short*)alloc((size_t)N * 128 * 2);
    unsigned short* acc  = (unsigned short*)alloc((size_t)N * 128 * 2);
    float* kvT_f = (float*)alloc((size_t)B * 2 * 64 * 64 * 4);
    float* vsum  = (float*)alloc((size_t)B * 128 * 4);
    unsigned short* kvT_b = (unsigned short*)alloc((size_t)B * 2 * 64 * 64 * 2);
    float* ksum  = (float*)alloc((size_t)B * 128 * 4);
    float* denom = (float*)alloc((size_t)N * 2 * 4);
    float* dis   = (float*)alloc((size_t)N * 4);
    int* deg     = (int*)alloc((size_t)N * 4);
    int* rowstart= (int*)alloc((size_t)(N + 1) * 4);
    int* cursor  = (int*)alloc((size_t)N * 4);
    int* csr_col = (int*)alloc((size_t)E * 4);
    float* csr_w = (float*)alloc((size_t)E * 4);
    int* csr_att = (int*)alloc((size_t)E * 4);
    int* batch   = (int*)alloc((size_t)N * 4);
    int* ptr     = (int*)alloc((size_t)(B + 1) * 4);
    int nb = (N + 255) / 256;
    int* bsum    = (int*)alloc((size_t)nb * 4);
    float* msg   = out;   // [N,64] fp32 aliased onto d_out; k_out rewrites it last

    size_t kvreg = (size_t)B * 2 * 64 * 64 * 4 + (size_t)B * 128 * 4;

    hipMemsetAsync(deg,    0, (size_t)N * 4, stream);
    hipMemsetAsync(cursor, 0, (size_t)N * 4, stream);
    hipMemsetAsync(ksum,   0, (size_t)B * 128 * 4, stream);

    k_ptr  <<<1, 64, 0, stream>>>(nn, ptr, B);
    k_batch<<<B, 256, 0, stream>>>(ptr, batch);
    k_qk   <<<2048, 256, 0, stream>>>(x, Wq_w, Wq_b, Wk_w, Wk_b, q, kq, curA, acc, N);
    k_deg  <<<(E + 255) / 256, 256, 0, stream>>>(eidx, deg, E);
    k_dis  <<<(N + 255) / 256, 256, 0, stream>>>(deg, dis, N);
    k_scan1<<<nb, 256, 0, stream>>>(deg, rowstart, bsum, N);
    k_scan2<<<1, 512, 0, stream>>>(bsum, nb);
    k_scan3<<<nb, 256, 0, stream>>>(rowstart, bsum, N, E);
    k_fill <<<(E + 255) / 256, 256, 0, stream>>>(eidx, dis, rowstart, cursor, csr_col, csr_w, csr_att, eattr, E);
    k_msg  <<<2048, 256, 0, stream>>>(rowstart, csr_att, csr_w, bond, msg, N);
    k_ksum <<<(N + 255) / 256, 128, 0, stream>>>(kq, batch, ksum, N);
    k_denom<<<(N + 3) / 4, 256, 0, stream>>>(q, ksum, batch, nn, denom, N);

    int kvblocks = (N + CHUNK - 1) / CHUNK;
    int n4 = B * 2 * 64 * 64 / 4;
    for (int it = 0; it < 4; ++it) {
        hipMemsetAsync(kvT_f, 0, kvreg, stream);
        k_kv  <<<kvblocks, 256, 0, stream>>>(kq, curA, batch, kvT_f, vsum, N);
        k_cvt <<<(n4 + 255) / 256, 256, 0, stream>>>(kvT_f, kvT_b, n4);
        k_attn<<<(N + 63) / 64, 256, 0, stream>>>(q, kvT_b, vsum, denom, batch, curB, N);
        k_gcn <<<(N + 3) / 4, 256, 0, stream>>>(curA, msg, rowstart, csr_col, csr_w, curB, acc, N);
        unsigned short* tmp = curA; curA = curB; curB = tmp;
    }
    k_out<<<(N + 63) / 64, 256, 0, stream>>>(acc, Wo_w, Wo_b, out, N);
}